// Round 1
// 104.241 us; speedup vs baseline: 1.0033x; 1.0033x over previous
//
#include <hip/hip_runtime.h>
#include <math.h>

#define TOK 4096
#define DM  512
#define HF  2048
#define NE  8

typedef __bf16 bf16x8 __attribute__((ext_vector_type(8)));
typedef float  floatx16 __attribute__((ext_vector_type(16)));

// float -> bf16 (round-to-nearest-even), raw ushort bits
__device__ __forceinline__ unsigned short f2b(float f) {
    union { float f; unsigned u; } v; v.f = f;
    return (unsigned short)((v.u + 0x7fffu + ((v.u >> 16) & 1u)) >> 16);
}

// async global->LDS, 16 bytes per lane (dest = wave-uniform base + lane*16,
// global source address is PER-LANE -> used for perm-indirect A gather in fc1)
__device__ __forceinline__ void load_lds16(const void* g, void* l) {
    __builtin_amdgcn_global_load_lds(
        (__attribute__((address_space(1))) unsigned int*)g,
        (__attribute__((address_space(3))) unsigned int*)l, 16, 0, 0);
}

// 64x64 fp32->bf16 transpose tile, works at 256 or 1024 threads/block.
template <int NTHR>
__device__ __forceinline__ void transpose_tile(const float* __restrict__ src,
                                               unsigned short* __restrict__ dst,
                                               int K, int N, int k0, int n0) {
    __shared__ unsigned short tile[64][68];
#pragma unroll
    for (int i = 0; i < 1024 / NTHR; i++) {
        int it = threadIdx.x + i * NTHR;
        int r = it >> 4, tc = it & 15;
        const float4 v = *(const float4*)(src + (size_t)(k0 + r) * N + n0 + tc * 4);
        tile[r][tc * 4 + 0] = f2b(v.x);
        tile[r][tc * 4 + 1] = f2b(v.y);
        tile[r][tc * 4 + 2] = f2b(v.z);
        tile[r][tc * 4 + 3] = f2b(v.w);
    }
    __syncthreads();
#pragma unroll
    for (int i = 0; i < 1024 / NTHR; i++) {
        int it = threadIdx.x + i * NTHR;
        int nrow = it >> 4, tc = it & 15;
        ushort4 o;
        o.x = tile[tc * 4 + 0][nrow];
        o.y = tile[tc * 4 + 1][nrow];
        o.z = tile[tc * 4 + 2][nrow];
        o.w = tile[tc * 4 + 3][nrow];
        *(ushort4*)(dst + (size_t)(n0 + nrow) * K + k0 + tc * 4) = o;
    }
}

// Fused: router (blocks 0..1023, one wave per token) + W1 transpose (2048 blocks).
// Router also emits xb = bf16(x) in TOKEN order (replaces k_gather; fc1 stages
// with perm-indirect addresses). W1 transpose overlaps the routing phase.
__global__ __launch_bounds__(256)
void k_router_trW1(const float* __restrict__ x, const float* __restrict__ Wr,
                   const float* __restrict__ br, const float* __restrict__ W1,
                   int* __restrict__ routes, unsigned short* __restrict__ xb,
                   unsigned short* __restrict__ W1t) {
    if (blockIdx.x >= TOK / 4) {            // W1: [E][512][2048] -> [E][2048][512]
        int bt = blockIdx.x - TOK / 4;
        int e = bt >> 8, tile = bt & 255;   // 8 k-tiles x 32 n-tiles
        transpose_tile<256>(W1 + (size_t)e * DM * HF, W1t + (size_t)e * HF * DM,
                            DM, HF, (tile >> 5) * 64, (tile & 31) * 64);
        return;
    }
    int t = blockIdx.x * 4 + (threadIdx.x >> 6);
    int lane = threadIdx.x & 63;
    const float4* xr = (const float4*)(x + (size_t)t * DM);
    float4 v0 = xr[lane * 2 + 0];           // 8 consecutive d per lane
    float4 v1 = xr[lane * 2 + 1];
    float xv[8] = {v0.x, v0.y, v0.z, v0.w, v1.x, v1.y, v1.z, v1.w};

    union { unsigned short u[8]; int4 q; } pk;
#pragma unroll
    for (int k = 0; k < 8; k++) pk.u[k] = f2b(xv[k]);
    *(int4*)(xb + (size_t)t * DM + lane * 8) = pk.q;   // coalesced 16B/lane

    float acc[NE];
#pragma unroll
    for (int e = 0; e < NE; e++) acc[e] = 0.f;
#pragma unroll
    for (int k = 0; k < 8; k++) {
        const float* w = Wr + (size_t)(lane * 8 + k) * NE;
        float4 wa = *(const float4*)(w);
        float4 wb = *(const float4*)(w + 4);
        acc[0] += xv[k] * wa.x; acc[1] += xv[k] * wa.y;
        acc[2] += xv[k] * wa.z; acc[3] += xv[k] * wa.w;
        acc[4] += xv[k] * wb.x; acc[5] += xv[k] * wb.y;
        acc[6] += xv[k] * wb.z; acc[7] += xv[k] * wb.w;
    }
#pragma unroll
    for (int off = 32; off > 0; off >>= 1)
#pragma unroll
        for (int e = 0; e < NE; e++) acc[e] += __shfl_down(acc[e], off, 64);
    if (lane == 0) {
        int best = 0; float bv = acc[0] + br[0];
#pragma unroll
        for (int e = 1; e < NE; e++) {
            float v = acc[e] + br[e];
            if (v > bv) { bv = v; best = e; }   // strict > == first-max (jnp.argmax)
        }
        routes[t] = best;
    }
}

// Fused: organize (block 0, ballot-based, zero atomics) + W2 transpose (2048 blocks).
__global__ __launch_bounds__(1024)
void k_organize_trW2(const int* __restrict__ routes, const float* __restrict__ W2,
                     int* __restrict__ offsets, int* __restrict__ perm,
                     unsigned short* __restrict__ W2t) {
    if (blockIdx.x > 0) {                   // W2: [E][2048][512] -> [E][512][2048]
        int bt = blockIdx.x - 1;
        int e = bt >> 8, tile = bt & 255;   // 32 k-tiles x 8 n-tiles
        transpose_tile<1024>(W2 + (size_t)e * HF * DM, W2t + (size_t)e * DM * HF,
                             HF, DM, (tile >> 3) * 64, (tile & 7) * 64);
        return;
    }
    // 1024 threads, 16 waves, 4 tokens/thread. Per-wave counts+ranks via ballot.
    __shared__ int wcnt[16][NE], wbase[16][NE], off[NE + 1], tot[NE];
    int tid = threadIdx.x, lane = tid & 63, w = tid >> 6;
    int4 r4 = *(const int4*)&routes[tid * 4];
    int e_[4] = {r4.x, r4.y, r4.z, r4.w};
    unsigned long long below = (1ull << lane) - 1ull;
    int rank[4];
#pragma unroll
    for (int e = 0; e < NE; e++) {
        int c = 0;
#pragma unroll
        for (int j = 0; j < 4; j++) {
            unsigned long long m = __ballot(e_[j] == e);
            if (e_[j] == e) rank[j] = c + __popcll(m & below);
            c += __popcll(m);
        }
        if (lane == 0) wcnt[w][e] = c;
    }
    __syncthreads();
    if (tid < NE) {                          // prefix over waves, per expert
        int s = 0;
#pragma unroll
        for (int ww = 0; ww < 16; ww++) { wbase[ww][tid] = s; s += wcnt[ww][tid]; }
        tot[tid] = s;
    }
    __syncthreads();
    if (tid == 0) {
        int s = 0;
#pragma unroll
        for (int e = 0; e < NE; e++) { off[e] = s; s += tot[e]; }
        off[NE] = s;
    }
    __syncthreads();
#pragma unroll
    for (int j = 0; j < 4; j++) {
        int e = e_[j];
        perm[off[e] + wbase[w][e] + rank[j]] = tid * 4 + j;
    }
    if (tid < NE + 1) offsets[tid] = off[tid];
}

// Grouped GEMM: 128x128 block, 4 waves (2x2) of 64x64, BK=32,
// mfma_f32_32x32x16_bf16, double-buffered LDS, XOR bank swizzle on the
// global side of global_load_lds (0 conflicts).
// FC1: A is TOKEN-ordered xb; rows gathered via perm-indirect per-lane
//      global_load_lds source addresses (hoisted: row index is k-invariant).
//      Epilogue GELU(acc+b1) -> hg (bf16, expert-grouped).
// FC2 (KSPLIT=4): A = hg (grouped); K-slice partials -> pbuf[ks].
template <int KD, int ND, bool FC1, int KSPLIT>
__global__ __launch_bounds__(256)
void k_gemm(const unsigned short* __restrict__ A,
            const unsigned short* __restrict__ Bt,
            const float* __restrict__ bias,
            unsigned short* __restrict__ hg,
            float* __restrict__ pbuf,
            const int* __restrict__ offsets,
            const int* __restrict__ perm) {
    const int e  = blockIdx.z / KSPLIT;
    const int ks = blockIdx.z % KSPLIT;
    const int seg0 = offsets[e];
    const int cnt  = offsets[e + 1] - seg0;
    const int m0 = blockIdx.y * 128;
    if (m0 >= cnt) return;
    const int n0 = blockIdx.x * 128;

    __shared__ unsigned short As[2][128 * 32];
    __shared__ unsigned short Bs[2][128 * 32];

    const unsigned short* Bexp = Bt + (size_t)e * ND * KD;

    const int tid  = threadIdx.x;
    const int lane = tid & 63;
    const int wave = tid >> 6;
    const int wm = (wave >> 1) * 64;
    const int wn = (wave & 1) * 64;

    // staging sources, hoisted (k-invariant). phys slot (row = fo>>6,
    // pc = (fo>>4)&3) holds global chunk c = pc ^ ((row>>1)&3).
    const unsigned short* aSrc[2];
    const unsigned short* bSrc[2];
    int fo_[2];
#pragma unroll
    for (int r = 0; r < 2; r++) {
        int fo  = tid * 16 + r * 4096;
        int row = fo >> 6;
        int c   = ((fo >> 4) & 3) ^ ((row >> 1) & 3);
        fo_[r] = fo;
        if constexpr (FC1) {
            int idx = seg0 + m0 + row;             // clamp: tail rows never stored
            if (idx > TOK - 1) idx = TOK - 1;
            aSrc[r] = A + (size_t)perm[idx] * KD + c * 8;   // token-order xb
        } else {
            aSrc[r] = A + (size_t)(seg0 + m0 + row) * KD + c * 8;  // grouped hg
        }
        bSrc[r] = Bexp + (size_t)(n0 + row) * KD + c * 8;
    }
    auto stage = [&](int k0, int buf) {
#pragma unroll
        for (int r = 0; r < 2; r++) {
            load_lds16(aSrc[r] + k0, (char*)As[buf] + fo_[r]);
            load_lds16(bSrc[r] + k0, (char*)Bs[buf] + fo_[r]);
        }
    };

    // fragment read addressing (32x32x16: m/n = lane&31, k = (lane>>5)*8 + j)
    const int fr = lane & 31;
    const int hi = lane >> 5;
    const int q  = (lane >> 1) & 3;
    const int sw[2] = { ((0 + hi) ^ q) * 8, ((2 + hi) ^ q) * 8 };
    const int aBase = (wm + fr) * 32;
    const int bBase = (wn + fr) * 32;

    floatx16 acc[2][2];
#pragma unroll
    for (int i = 0; i < 2; i++)
#pragma unroll
        for (int j = 0; j < 2; j++)
#pragma unroll
            for (int r = 0; r < 16; r++) acc[i][j][r] = 0.f;

    const int kBase = ks * (KD / KSPLIT);
    const int kEnd  = kBase + (KD / KSPLIT);
    stage(kBase, 0);
    int cur = 0;
    for (int k0 = kBase; k0 < kEnd; k0 += 32) {
        __syncthreads();
        if (k0 + 32 < kEnd) stage(k0 + 32, cur ^ 1);
#pragma unroll
        for (int kk = 0; kk < 2; kk++) {
            bf16x8 af[2], bf[2];
#pragma unroll
            for (int i = 0; i < 2; i++)
                af[i] = *(const bf16x8*)&As[cur][aBase + i * 1024 + sw[kk]];
#pragma unroll
            for (int j = 0; j < 2; j++)
                bf[j] = *(const bf16x8*)&Bs[cur][bBase + j * 1024 + sw[kk]];
#pragma unroll
            for (int i = 0; i < 2; i++)
#pragma unroll
                for (int j = 0; j < 2; j++)
                    acc[i][j] = __builtin_amdgcn_mfma_f32_32x32x16_bf16(af[i], bf[j], acc[i][j], 0, 0, 0);
        }
        cur ^= 1;
    }

    // epilogue: 32x32 C/D layout col=lane&31, row=(reg&3)+8*(reg>>2)+4*(lane>>5)
    const int rbase = 4 * hi;
#pragma unroll
    for (int i = 0; i < 2; i++) {
#pragma unroll
        for (int j = 0; j < 2; j++) {
            int col = n0 + wn + j * 32 + fr;
            float bv = FC1 ? bias[(size_t)e * ND + col] : 0.f;
#pragma unroll
            for (int r = 0; r < 16; r++) {
                int grow = m0 + wm + i * 32 + rbase + (r & 3) + 8 * (r >> 2);
                if (grow < cnt) {
                    float v = acc[i][j][r] + bv;
                    if constexpr (FC1) {
                        v = 0.5f * v * (1.0f + erff(v * 0.70710678118654752f)); // exact GELU
                        hg[(size_t)(seg0 + grow) * ND + col] = f2b(v);
                    } else {
                        pbuf[((size_t)ks * TOK + seg0 + grow) * ND + col] = v;
                    }
                }
            }
        }
    }
}

// out[perm[g]][:] = sum_ks pbuf[ks][g][:] + b2[e(g)][:]
__global__ __launch_bounds__(128)
void k_reduce(const float* __restrict__ pbuf, const int* __restrict__ perm,
              const int* __restrict__ offsets, const float* __restrict__ b2,
              float* __restrict__ out) {
    int g = blockIdx.x;
    int tok = perm[g];
    int e = 0;
#pragma unroll
    for (int i = 1; i < NE; i++) e += (g >= offsets[i]);
    int c = threadIdx.x * 4;
    float4 o = *(const float4*)&b2[(size_t)e * DM + c];
#pragma unroll
    for (int ks = 0; ks < 4; ks++) {
        float4 a = *(const float4*)&pbuf[((size_t)ks * TOK + g) * DM + c];
        o.x += a.x; o.y += a.y; o.z += a.z; o.w += a.w;
    }
    *(float4*)&out[(size_t)tok * DM + c] = o;
}

extern "C" void kernel_launch(void* const* d_in, const int* in_sizes, int n_in,
                              void* d_out, int out_size, void* d_ws, size_t ws_size,
                              hipStream_t stream) {
    const float* x  = (const float*)d_in[0];
    const float* Wr = (const float*)d_in[1];
    const float* br = (const float*)d_in[2];
    const float* W1 = (const float*)d_in[3];
    const float* b1 = (const float*)d_in[4];
    const float* W2 = (const float*)d_in[5];
    const float* b2 = (const float*)d_in[6];
    float* out = (float*)d_out;

    char* ws = (char*)d_ws;
    int* routes  = (int*)ws;            // [4096]
    int* perm    = routes + TOK;        // [4096]
    int* offsets = perm + TOK;          // [9]
    unsigned short* xb  = (unsigned short*)(ws + 65536);     // [4096][512]  bf16 token-order (4 MB)
    unsigned short* hg  = xb + (size_t)TOK * DM;             // [4096][2048] bf16 grouped (16 MB)
    unsigned short* W1t = hg + (size_t)TOK * HF;             // [E][H][D]    bf16 (16.8 MB)
    unsigned short* W2t = W1t + (size_t)NE * HF * DM;        // [E][D][H]    bf16 (16.8 MB)
    float* pbuf = (float*)(W2t + (size_t)NE * DM * HF);      // [4][4096][512] fp32 (33.5 MB)
    // FC2 A-tile overruns past hg end land in W1t (valid memory, non-NaN bf16);
    // rows >= cnt never stored. FC1 A rows are perm-clamped (no overrun).

    // 1: router (+ token-order bf16 x) || W1 transpose
    k_router_trW1<<<TOK / 4 + 2048, 256, 0, stream>>>(x, Wr, br, W1, routes, xb, W1t);
    // 2: ballot organize (1 block) || W2 transpose (2048 blocks keep chip busy)
    k_organize_trW2<<<2049, 1024, 0, stream>>>(routes, W2, offsets, perm, W2t);
    // 3: fc1, perm-gather fused into A staging
    k_gemm<DM, HF, true, 1><<<dim3(HF / 128, TOK / 128, NE), 256, 0, stream>>>(
        xb, W1t, b1, hg, nullptr, offsets, perm);
    // 4: fc2, split-K=4 -> ~576 active blocks; no atomics
    k_gemm<HF, DM, false, 4><<<dim3(DM / 128, TOK / 128, NE * 4), 256, 0, stream>>>(
        hg, W2t, nullptr, nullptr, pbuf, offsets, perm);
    // 5: reduce + bias + scatter
    k_reduce<<<TOK, 128, 0, stream>>>(pbuf, perm, offsets, b2, out);
}